// Round 6
// baseline (805.886 us; speedup 1.0000x reference)
//
#include <hip/hip_runtime.h>
#include <hip/hip_bf16.h>

#define VOCAB 29
#define VEC   512
#define HID   1024
#define SEN   64
#define BATCH 2048

typedef __bf16 bf16_t;
typedef bf16_t bf16x8 __attribute__((ext_vector_type(8)));
typedef float  floatx4 __attribute__((ext_vector_type(4)));

// ---------------- prep: W_hh fp32 -> bf16 ----------------
__global__ void cvt_whh(const float* __restrict__ w, bf16_t* __restrict__ o, int n) {
    int i = blockIdx.x * blockDim.x + threadIdx.x;
    if (i < n) o[i] = (bf16_t)w[i];
}

// ---------------- prep: W_cls fp32 [65][1024] -> bf16 padded [80][1024] ----------------
__global__ void cvt_wcls(const float* __restrict__ w, bf16_t* __restrict__ o) {
    int i = blockIdx.x * blockDim.x + threadIdx.x;
    if (i >= 80 * HID) return;
    o[i] = (i < 65 * HID) ? (bf16_t)w[i] : (bf16_t)0.0f;
}

// ---------------- prep: proj[v][h] = dot(emb[v], W_ih[h]) (fp32) ----------------
__global__ void proj_kernel(const float* __restrict__ emb, const float* __restrict__ wih,
                            float* __restrict__ proj) {
    int idx = blockIdx.x * blockDim.x + threadIdx.x;
    if (idx >= VOCAB * HID) return;
    int v = idx / HID, h = idx % HID;
    const float* e = emb + v * VEC;
    const float* w = wih + h * VEC;
    float s = 0.f;
    for (int k = 0; k < VEC; k += 4) {
        float4 ev = *(const float4*)(e + k);
        float4 wv = *(const float4*)(w + k);
        s += ev.x * wv.x + ev.y * wv.y + ev.z * wv.z + ev.w * wv.w;
    }
    proj[idx] = s;
}

// exact identity tanh(x) = 1 - 2/(exp(2x)+1); fp32 rounding error << bf16 ulp
__device__ __forceinline__ float fast_tanh(float x) {
    float e = __expf(2.0f * x);
    return 1.0f - 2.0f / (e + 1.0f);
}

// async global->LDS 16B copy (wave-uniform LDS base + lane*16)
__device__ __forceinline__ void load16_to_lds(const bf16_t* g, bf16_t* l) {
    auto gp = reinterpret_cast<const __attribute__((address_space(1))) unsigned int*>(
        reinterpret_cast<uintptr_t>(g));
    auto lp = reinterpret_cast<__attribute__((address_space(3))) unsigned int*>(
        static_cast<unsigned int>(reinterpret_cast<uintptr_t>(l)));
    __builtin_amdgcn_global_load_lds(gp, lp, 16, 0, 0);
}

// Non-draining barriers: waitcnt+barrier fused in ONE asm block so the compiler
// cannot prepend its conservative s_waitcnt vmcnt(0).
#define BARRIER_VM6()  asm volatile("s_waitcnt vmcnt(6)\n\ts_barrier" ::: "memory")
#define BARRIER_VM0()  asm volatile("s_waitcnt vmcnt(0)\n\ts_barrier" ::: "memory")
#define BARRIER_LGKM() asm volatile("s_waitcnt lgkmcnt(0)\n\ts_barrier" ::: "memory")

// ---------------- RNN step: h_out = tanh(proj[x[:,t]] + h_in @ W_hh^T) ----------------
// BM=128, BN=64, grid (16,16)=256 blocks (1/CU), 256 thr = 4 waves, wave tile 32x64.
// Triple-buffered LDS, DMA issued 2 tiles ahead, vmcnt(6) barriers (never drain to 0
// mid-loop). 6 DMA instructions per tile per wave; vmem retires in order (m135), so
// vmcnt(6) == "tile i landed, tiles i+1/i+2 may still fly".
// Race-freedom of buffer recycle: barrier at iter-i top separates all waves'
// iter-(i-1) compute (buf (i-1)%3) from this iter's issue into (i+2)%3 == (i-1)%3.
#define BM 128
#define BN 64
#define BK 64

__global__ __launch_bounds__(256)
void rnn_step(const bf16_t* __restrict__ h_in, const bf16_t* __restrict__ whh,
              const float* __restrict__ proj, const int* __restrict__ x,
              bf16_t* __restrict__ h_out, int t, int first)
{
    __shared__ __align__(16) bf16_t Ash[3][BM][BK];   // 48 KB
    __shared__ __align__(16) bf16_t Bsh[3][BN][BK];   // 24 KB
    __shared__ int tok_sh[BM];

    const int tid  = threadIdx.x;
    const int m0   = blockIdx.x * BM;
    const int n0   = blockIdx.y * BN;
    const int wave = tid >> 6;
    const int lane = tid & 63;
    const int wm   = wave * 32;        // 4 waves split m
    const int q    = lane >> 4;
    const int l16  = lane & 15;

    if (tid < BM) tok_sh[tid] = x[(m0 + tid) * SEN + t];

    // staging sources: chunk c = it*256 + wave*64 + lane; row r=c>>3, phys p=c&7,
    // global chunk g = p ^ (r&7)  (XOR swizzle; LDS dests stay lane-linear)
    const bf16_t* srcA[4];
    const bf16_t* srcB[2];
    int dstA[4], dstB[2];
#pragma unroll
    for (int it = 0; it < 4; it++) {
        int c = it * 256 + wave * 64 + lane;
        int r = c >> 3, p = c & 7, g = p ^ (r & 7);
        srcA[it] = h_in + (m0 + r) * HID + g * 8;
        dstA[it] = (it * 256 + wave * 64) * 8;
    }
#pragma unroll
    for (int it = 0; it < 2; it++) {
        int c = it * 256 + wave * 64 + lane;
        int r = c >> 3, p = c & 7, g = p ^ (r & 7);
        srcB[it] = whh + (n0 + r) * HID + g * 8;
        dstB[it] = (it * 256 + wave * 64) * 8;
    }

    floatx4 acc[2][4];
#pragma unroll
    for (int i = 0; i < 2; i++)
#pragma unroll
        for (int j = 0; j < 4; j++) acc[i][j] = (floatx4){0.f, 0.f, 0.f, 0.f};

    if (!first) {
        // prologue: prefetch tiles 0 and 1
#pragma unroll
        for (int it = 0; it < 4; it++) load16_to_lds(srcA[it], &Ash[0][0][0] + dstA[it]);
#pragma unroll
        for (int it = 0; it < 2; it++) load16_to_lds(srcB[it], &Bsh[0][0][0] + dstB[it]);
#pragma unroll
        for (int it = 0; it < 4; it++) load16_to_lds(srcA[it] + BK, &Ash[1][0][0] + dstA[it]);
#pragma unroll
        for (int it = 0; it < 2; it++) load16_to_lds(srcB[it] + BK, &Bsh[1][0][0] + dstB[it]);
    }
    BARRIER_LGKM();   // tok_sh visible; t0/t1 DMA stays in flight

    if (!first) {
        for (int i = 0; i < 16; i++) {
            // wait: tile i landed (6 newest vmem may remain) — then barrier
            if (i < 15) { BARRIER_VM6(); } else { BARRIER_VM0(); }
            const int buf = i % 3;
            if (i < 14) {
                const int koff = (i + 2) * BK;
                const int nb   = (i + 2) % 3;
#pragma unroll
                for (int it = 0; it < 4; it++)
                    load16_to_lds(srcA[it] + koff, &Ash[nb][0][0] + dstA[it]);
#pragma unroll
                for (int it = 0; it < 2; it++)
                    load16_to_lds(srcB[it] + koff, &Bsh[nb][0][0] + dstB[it]);
            }
#pragma unroll
            for (int ks = 0; ks < BK; ks += 32) {
                const int pq = (((ks >> 3) + q) ^ (l16 & 7)) * 8;
                bf16x8 af[2], bfr[4];
                af[0]  = *(const bf16x8*)&Ash[buf][wm + l16][pq];
                af[1]  = *(const bf16x8*)&Ash[buf][wm + 16 + l16][pq];
                bfr[0] = *(const bf16x8*)&Bsh[buf][l16][pq];
                bfr[1] = *(const bf16x8*)&Bsh[buf][16 + l16][pq];
                bfr[2] = *(const bf16x8*)&Bsh[buf][32 + l16][pq];
                bfr[3] = *(const bf16x8*)&Bsh[buf][48 + l16][pq];
#pragma unroll
                for (int mi = 0; mi < 2; mi++)
#pragma unroll
                    for (int ni = 0; ni < 4; ni++)
                        acc[mi][ni] = __builtin_amdgcn_mfma_f32_16x16x32_bf16(
                            af[mi], bfr[ni], acc[mi][ni], 0, 0, 0);
            }
        }
    }

    // epilogue: C/D row = q*4+reg, col = l16 (HW-verified); + proj + tanh
#pragma unroll
    for (int mi = 0; mi < 2; mi++) {
#pragma unroll
        for (int r = 0; r < 4; r++) {
            int lm = wm + mi * 16 + q * 4 + r;
            int gm = m0 + lm;
            const float* pr = proj + tok_sh[lm] * HID;
#pragma unroll
            for (int ni = 0; ni < 4; ni++) {
                int gn = n0 + ni * 16 + l16;
                float v = acc[mi][ni][r] + pr[gn];
                h_out[gm * HID + gn] = (bf16_t)fast_tanh(v);
            }
        }
    }
}

// ---------------- classifier: out = h @ W_cls^T + b_cls via MFMA (proven) ----------------
#define CBM 128
#define CLDK 72
__global__ __launch_bounds__(256)
void classifier_mfma(const bf16_t* __restrict__ h, const bf16_t* __restrict__ wcls,
                     const float* __restrict__ bcls, float* __restrict__ out)
{
    __shared__ __align__(16) bf16_t Ash[CBM][CLDK];
    __shared__ __align__(16) bf16_t Bsh[80][CLDK];

    const int tid = threadIdx.x;
    const int m0 = blockIdx.x * CBM;
    const int wave = tid >> 6, lane = tid & 63;
    const int wm = wave * 32;
    const int q = lane >> 4, l16 = lane & 15;

    floatx4 acc[2][5];
#pragma unroll
    for (int i = 0; i < 2; i++)
#pragma unroll
        for (int j = 0; j < 5; j++) acc[i][j] = (floatx4){0.f, 0.f, 0.f, 0.f};

    for (int kk = 0; kk < HID; kk += 64) {
#pragma unroll
        for (int it = 0; it < 4; it++) {
            int idx = tid + it * 256, r = idx >> 3, c = (idx & 7) * 8;
            *(uint4*)&Ash[r][c] = *(const uint4*)&h[(m0 + r) * HID + kk + c];
        }
#pragma unroll
        for (int it = 0; it < 3; it++) {
            int idx = tid + it * 256;
            if (idx < 640) {
                int r = idx >> 3, c = (idx & 7) * 8;
                *(uint4*)&Bsh[r][c] = *(const uint4*)&wcls[r * HID + kk + c];
            }
        }
        __syncthreads();
#pragma unroll
        for (int ks = 0; ks < 64; ks += 32) {
            bf16x8 af[2], bfr[5];
#pragma unroll
            for (int mi = 0; mi < 2; mi++)
                af[mi] = *(const bf16x8*)&Ash[wm + mi * 16 + l16][ks + q * 8];
#pragma unroll
            for (int ni = 0; ni < 5; ni++)
                bfr[ni] = *(const bf16x8*)&Bsh[ni * 16 + l16][ks + q * 8];
#pragma unroll
            for (int mi = 0; mi < 2; mi++)
#pragma unroll
                for (int ni = 0; ni < 5; ni++)
                    acc[mi][ni] = __builtin_amdgcn_mfma_f32_16x16x32_bf16(
                        af[mi], bfr[ni], acc[mi][ni], 0, 0, 0);
        }
        __syncthreads();
    }

#pragma unroll
    for (int mi = 0; mi < 2; mi++) {
#pragma unroll
        for (int r = 0; r < 4; r++) {
            int gm = m0 + wm + mi * 16 + q * 4 + r;
#pragma unroll
            for (int ni = 0; ni < 5; ni++) {
                int gn = ni * 16 + l16;
                if (gn < SEN + 1)
                    out[gm * (SEN + 1) + gn] = acc[mi][ni][r] + bcls[gn];
            }
        }
    }
}

extern "C" void kernel_launch(void* const* d_in, const int* in_sizes, int n_in,
                              void* d_out, int out_size, void* d_ws, size_t ws_size,
                              hipStream_t stream)
{
    const int*   x     = (const int*)  d_in[0];
    const float* emb   = (const float*)d_in[1];
    const float* w_ih  = (const float*)d_in[2];
    const float* w_hh  = (const float*)d_in[3];
    const float* w_cls = (const float*)d_in[4];
    const float* b_cls = (const float*)d_in[5];
    float* out = (float*)d_out;

    char* ws = (char*)d_ws;
    bf16_t* whh_bf  = (bf16_t*)ws;                                  // 2 MB
    float*  proj    = (float*)(ws + (2u << 20));                    // 128 KB
    bf16_t* wcls_bf = (bf16_t*)(ws + (2u << 20) + (128u << 10));    // 160 KB
    bf16_t* h0      = (bf16_t*)(ws + (2u << 20) + (288u << 10));    // 4 MB
    bf16_t* h1      = (bf16_t*)(ws + (6u << 20) + (288u << 10));    // 4 MB

    cvt_whh<<<(HID * HID) / 256, 256, 0, stream>>>(w_hh, whh_bf, HID * HID);
    proj_kernel<<<(VOCAB * HID + 255) / 256, 256, 0, stream>>>(emb, w_ih, proj);
    cvt_wcls<<<(80 * HID) / 256, 256, 0, stream>>>(w_cls, wcls_bf);

    dim3 grid(BATCH / BM, HID / BN);   // (16,16) = 256 blocks
    bf16_t* bufs[2] = {h0, h1};
    for (int t = 0; t < SEN; t++) {
        bf16_t* hi = bufs[(t + 1) & 1];   // ignored when t==0 (first=1)
        bf16_t* ho = bufs[t & 1];
        rnn_step<<<grid, 256, 0, stream>>>(hi, whh_bf, proj, x, ho, t, t == 0 ? 1 : 0);
    }
    classifier_mfma<<<BATCH / CBM, 256, 0, stream>>>(bufs[1], wcls_bf, b_cls, out);
}